// Round 1
// baseline (1834.365 us; speedup 1.0000x reference)
//
#include <hip/hip_runtime.h>
#include <hip/hip_bf16.h>
#include <math.h>

// Performer (FAVOR+) attention forward, fp32.
// B=4 H=12 N=4096 D=64 M=256. BH=48.
//
// Pipeline:
//   memset ws(ctx,ksum) -> kmax_kernel (global max of k_dash) -> kmax_reduce
//   -> kctx_kernel (ctx[m,d], ksum[m] via atomics) -> qout_kernel (fused q')
//
// ratio = M^-0.5 cancels between numerator and denominator -> omitted.
// mask & 1/8 scaling folded into per-row constants so inner loops use RAW
// K/V/Q rows via wave-uniform loads (compiler scalarizes to s_load).

#define BH 48
#define NSEQ 4096
#define DD 64
#define MM 256
#define EPSF 1e-4f

__device__ __forceinline__ float waveMax(float v) {
    v = fmaxf(v, __shfl_xor(v, 32));
    v = fmaxf(v, __shfl_xor(v, 16));
    v = fmaxf(v, __shfl_xor(v, 8));
    v = fmaxf(v, __shfl_xor(v, 4));
    v = fmaxf(v, __shfl_xor(v, 2));
    v = fmaxf(v, __shfl_xor(v, 1));
    return v;
}

// ---------------- Kernel A: global max of k_dash ----------------
// grid = BH*16 blocks, 256 threads. Each block: 256 rows, thread t owns m=t.
__global__ __launch_bounds__(256) void kmax_kernel(
    const float* __restrict__ K, const float* __restrict__ mask,
    const float* __restrict__ proj, float* __restrict__ apart) {
    const int t = threadIdx.x;
    const int bh = blockIdx.x >> 4;
    const int chunk = blockIdx.x & 15;
    const int b = bh / 12;
    const int row0 = chunk * 256;
    const float* __restrict__ Kb = K + (size_t)bh * NSEQ * DD;
    const float* __restrict__ mk = mask + (size_t)b * NSEQ;

    float pj[64];
    {
        const float4* pr = (const float4*)(proj + t * DD);
        #pragma unroll
        for (int i = 0; i < 16; ++i) {
            float4 v = pr[i];
            pj[4*i] = v.x; pj[4*i+1] = v.y; pj[4*i+2] = v.z; pj[4*i+3] = v.w;
        }
    }
    float mx = -INFINITY;
    for (int r0 = 0; r0 < 256; ++r0) {
        const int r = row0 + r0;
        const float* __restrict__ kr = Kb + (size_t)r * DD;  // wave-uniform
        float a = mk[r] * 0.125f;                             // wave-uniform
        float d0 = 0.f, d1 = 0.f, d2 = 0.f, d3 = 0.f;
        #pragma unroll
        for (int j = 0; j < 64; j += 4) {
            d0 = fmaf(kr[j+0], pj[j+0], d0);
            d1 = fmaf(kr[j+1], pj[j+1], d1);
            d2 = fmaf(kr[j+2], pj[j+2], d2);
            d3 = fmaf(kr[j+3], pj[j+3], d3);
        }
        mx = fmaxf(mx, ((d0 + d1) + (d2 + d3)) * a);
    }
    mx = waveMax(mx);
    __shared__ float wmax[4];
    if ((t & 63) == 0) wmax[t >> 6] = mx;
    __syncthreads();
    if (t == 0)
        apart[blockIdx.x] = fmaxf(fmaxf(wmax[0], wmax[1]), fmaxf(wmax[2], wmax[3]));
}

__global__ __launch_bounds__(256) void kmax_reduce(
    const float* __restrict__ apart, float* __restrict__ mxout) {
    float v = -INFINITY;
    for (int i = threadIdx.x; i < BH * 16; i += 256) v = fmaxf(v, apart[i]);
    v = waveMax(v);
    __shared__ float w[4];
    if ((threadIdx.x & 63) == 0) w[threadIdx.x >> 6] = v;
    __syncthreads();
    if (threadIdx.x == 0)
        mxout[0] = fmaxf(fmaxf(w[0], w[1]), fmaxf(w[2], w[3]));
}

// ---------------- Kernel B: ctx and ksum ----------------
// grid = BH*8 blocks (512 rows each), 256 threads, thread t owns m=t.
// acc[d] (64 VGPR) accumulates ctx[m=t][d]; atomicAdd at the end.
__global__ __launch_bounds__(256) void kctx_kernel(
    const float* __restrict__ K, const float* __restrict__ V,
    const float* __restrict__ mask, const float* __restrict__ proj,
    const float* __restrict__ wsmx, float* __restrict__ ctx,
    float* __restrict__ ksum) {
    const int t = threadIdx.x;
    const int bh = blockIdx.x >> 3;
    const int chunk = blockIdx.x & 7;
    const int b = bh / 12;
    const float MX = wsmx[0];
    const float* __restrict__ Kb = K + (size_t)bh * NSEQ * DD;
    const float* __restrict__ Vb = V + (size_t)bh * NSEQ * DD;
    const float* __restrict__ mk = mask + (size_t)b * NSEQ;

    float pj[64];
    {
        const float4* pr = (const float4*)(proj + t * DD);
        #pragma unroll
        for (int i = 0; i < 16; ++i) {
            float4 v = pr[i];
            pj[4*i] = v.x; pj[4*i+1] = v.y; pj[4*i+2] = v.z; pj[4*i+3] = v.w;
        }
    }
    float acc[64];
    #pragma unroll
    for (int j = 0; j < 64; ++j) acc[j] = 0.f;
    float ks = 0.f;

    __shared__ float lds_a[64], lds_c[64], lds_vm[64];

    for (int sub = 0; sub < 8; ++sub) {
        const int r0 = chunk * 512 + sub * 64;
        // cooperative sum-of-squares for 64 rows (4 threads/row, 16 elems each)
        {
            int rr = t >> 2, seg = t & 3;
            const float4* kq = (const float4*)(Kb + (size_t)(r0 + rr) * DD + seg * 16);
            float s = 0.f;
            #pragma unroll
            for (int i = 0; i < 4; ++i) {
                float4 v = kq[i];
                s += v.x*v.x + v.y*v.y + v.z*v.z + v.w*v.w;
            }
            s += __shfl_xor(s, 1);
            s += __shfl_xor(s, 2);
            if (seg == 0) {
                float m = mk[r0 + rr];
                lds_a[rr] = m * 0.125f;
                lds_vm[rr] = m;
                lds_c[rr] = -(m * m) * (s * (1.f / 128.f)) - MX;
            }
        }
        __syncthreads();
        for (int r = 0; r < 64; ++r) {
            const float* __restrict__ kr = Kb + (size_t)(r0 + r) * DD;  // uniform
            const float* __restrict__ vr = Vb + (size_t)(r0 + r) * DD;  // uniform
            float a = lds_a[r], c = lds_c[r], vm = lds_vm[r];
            float d0 = 0.f, d1 = 0.f, d2 = 0.f, d3 = 0.f;
            #pragma unroll
            for (int j = 0; j < 64; j += 4) {
                d0 = fmaf(kr[j+0], pj[j+0], d0);
                d1 = fmaf(kr[j+1], pj[j+1], d1);
                d2 = fmaf(kr[j+2], pj[j+2], d2);
                d3 = fmaf(kr[j+3], pj[j+3], d3);
            }
            float e = __expf(fmaf((d0 + d1) + (d2 + d3), a, c)) + EPSF;
            ks += e;                    // ksum has no outer mask factor
            float kpv = e * vm;         // v = V * mask folded here
            #pragma unroll
            for (int j = 0; j < 64; ++j) acc[j] = fmaf(vr[j], kpv, acc[j]);
        }
        __syncthreads();
    }
    float* cdst = ctx + ((size_t)bh * MM + t) * DD;
    #pragma unroll
    for (int j = 0; j < 64; ++j) atomicAdd(cdst + j, acc[j]);
    atomicAdd(ksum + (size_t)bh * MM + t, ks);
}

// ---------------- Kernel C: fused q' -> out ----------------
// grid = BH*(N/16) blocks, 256 threads. 16 rows/block.
__global__ __launch_bounds__(256) void qout_kernel(
    const float* __restrict__ Q, const float* __restrict__ proj,
    const float* __restrict__ ctx, const float* __restrict__ ksum,
    float* __restrict__ out) {
    const int t = threadIdx.x;
    const int bh = blockIdx.x >> 8;
    const int tile = blockIdx.x & 255;
    const int row0 = tile * 16;
    const float* __restrict__ Qb = Q + (size_t)bh * NSEQ * DD;

    __shared__ float qp[256][17];
    __shared__ float ssq[16], mxs[16], dnv[16];

    // phase 0: raw sum of squares per row (16 threads/row, 4 elems each)
    {
        int rr = t >> 4, seg = t & 15;
        const float4* qq = (const float4*)(Qb + (size_t)(row0 + rr) * DD + seg * 4);
        float4 v = qq[0];
        float s = v.x*v.x + v.y*v.y + v.z*v.z + v.w*v.w;
        s += __shfl_xor(s, 1);
        s += __shfl_xor(s, 2);
        s += __shfl_xor(s, 4);
        s += __shfl_xor(s, 8);
        if (seg == 0) ssq[rr] = s;
    }
    // phase 1: thread t owns m=t; dot each of 16 rows with proj[m]
    float pj[64];
    {
        const float4* pr = (const float4*)(proj + t * DD);
        #pragma unroll
        for (int i = 0; i < 16; ++i) {
            float4 v = pr[i];
            pj[4*i] = v.x; pj[4*i+1] = v.y; pj[4*i+2] = v.z; pj[4*i+3] = v.w;
        }
    }
    float qd[16];
    #pragma unroll
    for (int r = 0; r < 16; ++r) {
        const float* __restrict__ qr = Qb + (size_t)(row0 + r) * DD;  // uniform
        float d0 = 0.f, d1 = 0.f, d2 = 0.f, d3 = 0.f;
        #pragma unroll
        for (int j = 0; j < 64; j += 4) {
            d0 = fmaf(qr[j+0], pj[j+0], d0);
            d1 = fmaf(qr[j+1], pj[j+1], d1);
            d2 = fmaf(qr[j+2], pj[j+2], d2);
            d3 = fmaf(qr[j+3], pj[j+3], d3);
        }
        qd[r] = ((d0 + d1) + (d2 + d3)) * 0.125f;
        qp[t][r] = qd[r];
    }
    __syncthreads();
    // phase 3: row max over 256 m (16 threads/row)
    {
        int r = t >> 4, j = t & 15;
        float m = -INFINITY;
        #pragma unroll
        for (int i = 0; i < 16; ++i) m = fmaxf(m, qp[j * 16 + i][r]);
        m = fmaxf(m, __shfl_xor(m, 1));
        m = fmaxf(m, __shfl_xor(m, 2));
        m = fmaxf(m, __shfl_xor(m, 4));
        m = fmaxf(m, __shfl_xor(m, 8));
        if (j == 0) mxs[r] = m;
    }
    __syncthreads();
    // phase 4: q' (sans ratio)
    #pragma unroll
    for (int r = 0; r < 16; ++r) {
        float arg = qd[r] - ssq[r] * (1.f / 128.f) - mxs[r];
        qp[t][r] = __expf(arg) + EPSF;
    }
    __syncthreads();
    // phase 5: denom and reciprocal
    {
        int r = t >> 4, j = t & 15;
        const float* __restrict__ ksb = ksum + (size_t)bh * MM;
        float s = 0.f;
        #pragma unroll
        for (int i = 0; i < 16; ++i) {
            int m2 = j * 16 + i;
            s = fmaf(qp[m2][r], ksb[m2], s);
        }
        s += __shfl_xor(s, 1);
        s += __shfl_xor(s, 2);
        s += __shfl_xor(s, 4);
        s += __shfl_xor(s, 8);
        if (j == 0) dnv[r] = 1.f / s;
    }
    __syncthreads();
    // phase 6: out[r][c..c+3] = (sum_m qp[m][r]*ctx[m][c..]) * dinv[r]
    {
        int r = t >> 4, c = (t & 15) * 4;
        const float4* cb = (const float4*)(ctx + (size_t)bh * MM * DD + c);
        float4 acc = {0.f, 0.f, 0.f, 0.f};
        #pragma unroll 4
        for (int m2 = 0; m2 < 256; ++m2) {
            float q = qp[m2][r];
            float4 cv = cb[(size_t)m2 * 16];
            acc.x = fmaf(q, cv.x, acc.x);
            acc.y = fmaf(q, cv.y, acc.y);
            acc.z = fmaf(q, cv.z, acc.z);
            acc.w = fmaf(q, cv.w, acc.w);
        }
        float di = dnv[r];
        acc.x *= di; acc.y *= di; acc.z *= di; acc.w *= di;
        *(float4*)(out + ((size_t)bh * NSEQ + row0 + r) * DD + c) = acc;
    }
}

extern "C" void kernel_launch(void* const* d_in, const int* in_sizes, int n_in,
                              void* d_out, int out_size, void* d_ws, size_t ws_size,
                              hipStream_t stream) {
    const float* Q    = (const float*)d_in[0];
    const float* K    = (const float*)d_in[1];
    const float* V    = (const float*)d_in[2];
    const float* mask = (const float*)d_in[3];
    const float* proj = (const float*)d_in[4];
    float* out = (float*)d_out;
    float* ws  = (float*)d_ws;

    float* mx    = ws;            // [0]
    float* apart = ws + 64;       // 768 block maxima
    float* ksum  = ws + 1024;     // BH*256
    float* ctx   = ws + 16384;    // BH*256*64  (ends at 802816 floats = 3.2 MB)

    // zero the atomically-accumulated region (ksum..ctx end)
    hipMemsetAsync(ksum, 0, (size_t)(802816 - 1024) * sizeof(float), stream);

    kmax_kernel<<<BH * 16, 256, 0, stream>>>(K, mask, proj, apart);
    kmax_reduce<<<1, 256, 0, stream>>>(apart, mx);
    kctx_kernel<<<BH * 8, 256, 0, stream>>>(K, V, mask, proj, mx, ctx, ksum);
    qout_kernel<<<BH * (NSEQ / 16), 256, 0, stream>>>(Q, proj, ctx, ksum, out);
}